// Round 19
// baseline (330.009 us; speedup 1.0000x reference)
//
#include <hip/hip_runtime.h>
#include <hip/hip_bf16.h>

#define NV 100000
#define NE 20000
#define NNZ 3200000
#define CHUNK2 8192
#define NBLK2 ((NNZ + CHUNK2 - 1) / CHUNK2)  // 391 (s3 part)
#define CVTB ((NV * 16 + 1023) / 1024)       // 1563 (cvt part, 1024 thr)
#define NBE 157      // E buckets: e>>7
#define NBV 196      // V buckets: v>>9
#define CAPE 23040
#define CAPV 17920

typedef float vf2 __attribute__((ext_vector_type(2)));

__device__ __forceinline__ unsigned short f2bf(float f) {
    unsigned u = __float_as_uint(f);
    u += 0x7fffu + ((u >> 16) & 1u);       // round-to-nearest-even
    return (unsigned short)(u >> 16);
}
__device__ __forceinline__ float2 bfu(unsigned u) {
    return make_float2(__uint_as_float(u << 16), __uint_as_float(u & 0xffff0000u));
}
template <bool HI>
__device__ __forceinline__ int pk8(float a, float b, int old) {
    return __builtin_amdgcn_cvt_pk_fp8_f32(a, b, old, HI);
}

// ---------------- S3 + cvt merged (1024 thr): blocks [0,NBLK2) bin; rest convert x ----------
__global__ __launch_bounds__(1024) void s3_bin_cvt(const int* __restrict__ vids,
                                                   const int* __restrict__ eids,
                                                   int* __restrict__ gcurE, int* __restrict__ gcurV,
                                                   unsigned* __restrict__ pkE, unsigned* __restrict__ pkV,
                                                   const float* __restrict__ xin,
                                                   unsigned char* __restrict__ xh8) {
    __shared__ int h[256], sc[256], gp[256];
    __shared__ unsigned staged[CHUNK2];        // 32 KB
    __shared__ unsigned char sb[CHUNK2];       // 8 KB
    int tid = threadIdx.x;
    if (blockIdx.x >= NBLK2) {
        // ---- cvt part ----
        int i = (blockIdx.x - NBLK2) * 1024 + tid;
        if (i < NV * 16) {
            float4 v0 = ((const float4*)xin)[i * 2];
            float4 v1 = ((const float4*)xin)[i * 2 + 1];
            int lo = pk8<false>(v0.x, v0.y, 0); lo = pk8<true>(v0.z, v0.w, lo);
            int hi = pk8<false>(v1.x, v1.y, 0); hi = pk8<true>(v1.z, v1.w, hi);
            ((int2*)xh8)[i] = make_int2(lo, hi);
        }
        return;
    }
    int base = blockIdx.x * CHUNK2;
    int n = NNZ - base; if (n > CHUNK2) n = CHUNK2;
    unsigned pe[8], pv[8];
#pragma unroll
    for (int k = 0; k < 8; ++k) {
        int i = base + k * 1024 + tid;
        pe[k] = 0u; pv[k] = 0u;
        if (i < NNZ) {
            unsigned e = (unsigned)eids[i], v = (unsigned)vids[i];
            pe[k] = (e << 17) | v;
            pv[k] = (v << 15) | e;
        }
    }
#define SIDE(pk_arr, PK, gcur, CAP) \
    { \
        if (tid < 256) h[tid] = 0; \
        __syncthreads(); \
        _Pragma("unroll") \
        for (int k = 0; k < 8; ++k) \
            if (base + k * 1024 + tid < NNZ) atomicAdd(&h[PK[k] >> 24], 1); \
        __syncthreads(); \
        if (tid < 256) sc[tid] = h[tid]; \
        __syncthreads(); \
        for (int o = 1; o < 256; o <<= 1) { \
            int v = (tid >= o && tid < 256) ? sc[tid - o] : 0; \
            __syncthreads(); \
            if (tid < 256) sc[tid] += v; \
            __syncthreads(); \
        } \
        if (tid < 256) { int ex = sc[tid] - h[tid]; h[tid] = ex; sc[tid] = ex; } \
        __syncthreads(); \
        _Pragma("unroll") \
        for (int k = 0; k < 8; ++k) \
            if (base + k * 1024 + tid < NNZ) { \
                int b = PK[k] >> 24; \
                int pos = atomicAdd(&h[b], 1); \
                staged[pos] = PK[k]; sb[pos] = (unsigned char)b; \
            } \
        __syncthreads(); \
        if (tid < 256) { int cnt = h[tid] - sc[tid]; gp[tid] = cnt ? atomicAdd(&gcur[tid], cnt) : 0; } \
        __syncthreads(); \
        for (int i = tid; i < n; i += 1024) { \
            int b = sb[i]; \
            pk_arr[(size_t)b * CAP + gp[b] + (i - sc[b])] = staged[i]; \
        } \
        __syncthreads(); \
    }
    SIDE(pkE, pe, gcurE, CAPE)
    SIDE(pkV, pv, gcurV, CAPV)
#undef SIDE
}

// ---------------- S2: scan bucket FILL COUNTS -> output bases; BN fold + w2a fold ----------------
__global__ void s2_scan(const int* __restrict__ gcurE, const int* __restrict__ gcurV,
                        int* __restrict__ bbE, int* __restrict__ bbV,
                        int* __restrict__ offE, int* __restrict__ offV,
                        const float* __restrict__ g, const float* __restrict__ b,
                        const float* __restrict__ mu, const float* __restrict__ var,
                        const float* __restrict__ w2a,
                        float* __restrict__ w2af, float* __restrict__ bias) {
    __shared__ float sh_s[128];
    int t = threadIdx.x;
    if (t < 128) {
        float sc = g[t] * rsqrtf(var[t] + 1e-5f);
        float sh = b[t] - mu[t] * sc;
        sh_s[t] = sh;
        for (int n = 0; n < 40; ++n)
            w2af[t * 40 + n] = sc * w2a[t * 40 + n];
    }
    __syncthreads();
    if (t < 40) {
        float acc = 0.f;
        for (int c = 0; c < 128; ++c)
            acc = fmaf(sh_s[c], w2a[c * 40 + t], acc);
        bias[t] = acc;
    }
    if (t == 0) {
        int run = 0;
        for (int bb = 0; bb < 256; ++bb) { bbE[bb] = run; run += gcurE[bb]; }
        bbE[256] = run; offE[NE] = run;
    } else if (t == 1) {
        int run = 0;
        for (int bb = 0; bb < 256; ++bb) { bbV[bb] = run; run += gcurV[bb]; }
        bbV[256] = run; offV[NV] = run;
    }
}

// ---------------- S4: per-bucket fine counting sort (reads fixed-cap bucket, writes CSR) ----
__global__ __launch_bounds__(1024) void s4_sort(const unsigned* __restrict__ pkE,
                                                const unsigned* __restrict__ pkV,
                                                const int* __restrict__ bbE, const int* __restrict__ bbV,
                                                int* __restrict__ offE, int* __restrict__ offV,
                                                int* __restrict__ srcE, int* __restrict__ srcV) {
    __shared__ int h[512], sc[512];
    int blk = blockIdx.x, tid = threadIdx.x;
    bool isE = blk < NBE;
    const unsigned* pk = isE ? pkE : pkV;
    const int* bb = isE ? bbE : bbV;
    int* off = isE ? offE : offV;
    int* srcO = isE ? srcE : srcV;
    int b = isE ? blk : blk - NBE;
    int NLOC = isE ? 128 : 512;
    int SH = isE ? 17 : 15;
    int LM = NLOC - 1;
    unsigned PM = isE ? 0x1FFFFu : 0x7FFFu;
    int d0 = isE ? (b << 7) : (b << 9);
    int nD = isE ? NE : NV;
    size_t inBase = (size_t)b * (isE ? CAPE : CAPV);
    int obase = bb[b];
    int cnt = bb[b + 1] - obase;
    if (tid < NLOC) h[tid] = 0;
    __syncthreads();
    for (int i = tid; i < cnt; i += 1024)
        atomicAdd(&h[(pk[inBase + i] >> SH) & LM], 1);
    __syncthreads();
    if (tid < NLOC) sc[tid] = h[tid];
    __syncthreads();
    for (int o = 1; o < NLOC; o <<= 1) {
        int v = (tid >= o && tid < NLOC) ? sc[tid - o] : 0;
        __syncthreads();
        if (tid < NLOC) sc[tid] += v;
        __syncthreads();
    }
    if (tid < NLOC) {
        int ex = sc[tid] - h[tid];
        int d = d0 + tid;
        if (d < nD) off[d] = obase + ex;
        h[tid] = ex;
    }
    __syncthreads();
    for (int i = tid; i < cnt; i += 1024) {
        unsigned p = pk[inBase + i];
        int pos = atomicAdd(&h[(p >> SH) & LM], 1);
        srcO[obase + pos] = (int)(p & PM);
    }
}

// ---------------- FUSED: y = relu(A@W1); y28 = fp8(y@W2); sequential LDS reuse (80 KB) ----------
__global__ __launch_bounds__(256) void mm12(const float* __restrict__ A,
                                            const float* __restrict__ W1,
                                            const float* __restrict__ W2,
                                            unsigned char* __restrict__ out8, int M) {
    __shared__ float Wl[128 * 128];   // 64 KB (W1, then W2)
    __shared__ float Al[32 * 128];    // 16 KB (A tile, then Y tile)
    int tid = threadIdx.x;
    for (int i = tid; i < 4096; i += 256)
        ((float4*)Wl)[i] = ((const float4*)W1)[i];
    int row0 = blockIdx.x * 32;
    for (int i = tid; i < 1024; i += 256) {
        int r = i >> 5, c4 = i & 31;
        int row = row0 + r;
        float4 v = make_float4(0.f, 0.f, 0.f, 0.f);
        if (row < M) v = ((const float4*)(A + (size_t)row * 128))[c4];
        ((float4*)Al)[i] = v;
    }
    __syncthreads();
    int cx = (tid & 31) * 4;
    int rg = (tid >> 5) * 4;
    float acc[4][4] = {};
#pragma unroll 8
    for (int k = 0; k < 128; ++k) {
        float4 w = *(const float4*)&Wl[k * 128 + cx];
#pragma unroll
        for (int r = 0; r < 4; ++r) {
            float a = Al[(rg + r) * 128 + k];
            acc[r][0] = fmaf(a, w.x, acc[r][0]);
            acc[r][1] = fmaf(a, w.y, acc[r][1]);
            acc[r][2] = fmaf(a, w.z, acc[r][2]);
            acc[r][3] = fmaf(a, w.w, acc[r][3]);
        }
    }
    __syncthreads();   // all reads of Al/Wl done
#pragma unroll
    for (int r = 0; r < 4; ++r)
        *(float4*)&Al[(rg + r) * 128 + cx] =
            make_float4(fmaxf(acc[r][0], 0.f), fmaxf(acc[r][1], 0.f),
                        fmaxf(acc[r][2], 0.f), fmaxf(acc[r][3], 0.f));
    for (int i = tid; i < 4096; i += 256)
        ((float4*)Wl)[i] = ((const float4*)W2)[i];
    __syncthreads();
    float acc2[4][4] = {};
#pragma unroll 8
    for (int k = 0; k < 128; ++k) {
        float4 w = *(const float4*)&Wl[k * 128 + cx];
#pragma unroll
        for (int r = 0; r < 4; ++r) {
            float a = Al[(rg + r) * 128 + k];
            acc2[r][0] = fmaf(a, w.x, acc2[r][0]);
            acc2[r][1] = fmaf(a, w.y, acc2[r][1]);
            acc2[r][2] = fmaf(a, w.z, acc2[r][2]);
            acc2[r][3] = fmaf(a, w.w, acc2[r][3]);
        }
    }
#pragma unroll
    for (int r = 0; r < 4; ++r) {
        int row = row0 + rg + r;
        if (row < M) {
            int pw = pk8<false>(acc2[r][0], acc2[r][1], 0);
            pw = pk8<true>(acc2[r][2], acc2[r][3], pw);
            *(int*)&out8[(size_t)row * 128 + cx] = pw;
        }
    }
}

// ---------------- FUSED: y3 = relu(A@W' + bias) in LDS; y4 = y3@W2 -> bf16 (stride-64) ----------
__global__ __launch_bounds__(256) void mm_fused40(const float* __restrict__ A,
                                                  const float* __restrict__ W1,
                                                  const float* __restrict__ bias,
                                                  const float* __restrict__ W2,
                                                  unsigned short* __restrict__ out16, int M) {
    __shared__ float Wl[128 * 40];    // 20 KB
    __shared__ float W2l[1600];       // 6.4 KB
    __shared__ float Al[24 * 128];    // 12 KB
    __shared__ float Yl[24 * 40];     // 3.84 KB
    int tid = threadIdx.x;
    for (int i = tid; i < 1280; i += 256)
        ((float4*)Wl)[i] = ((const float4*)W1)[i];
    for (int i = tid; i < 400; i += 256)
        ((float4*)W2l)[i] = ((const float4*)W2)[i];
    int row0 = blockIdx.x * 24;
    for (int i = tid; i < 768; i += 256) {
        int r = i >> 5, c4 = i & 31;
        int row = row0 + r;
        float4 v = make_float4(0.f, 0.f, 0.f, 0.f);
        if (row < M) v = ((const float4*)(A + (size_t)row * 128))[c4];
        ((float4*)Al)[i] = v;
    }
    __syncthreads();
    if (tid < 240) {
        int col = tid % 40;
        int rg = (tid / 40) * 4;
        float b0 = bias[col];
        float acc[4] = {b0, b0, b0, b0};
#pragma unroll 8
        for (int k = 0; k < 128; ++k) {
            float w = Wl[k * 40 + col];
#pragma unroll
            for (int r = 0; r < 4; ++r)
                acc[r] = fmaf(Al[(rg + r) * 128 + k], w, acc[r]);
        }
#pragma unroll
        for (int r = 0; r < 4; ++r)
            Yl[(rg + r) * 40 + col] = fmaxf(acc[r], 0.f);
    }
    __syncthreads();
    for (int idx = tid; idx < 960; idx += 256) {
        int row = idx / 40, col = idx % 40;
        float acc = 0.f;
#pragma unroll
        for (int k = 0; k < 40; ++k)
            acc = fmaf(Yl[row * 40 + k], W2l[k * 40 + col], acc);
        int grow = row0 + row;
        if (grow < M) out16[(size_t)grow * 64 + col] = f2bf(acc);
    }
}

// ============ E-side segment-mean, 128 fp8 ch, 8-lane groups, 4-deep MLP ============
__global__ __launch_bounds__(256) void segred128e8(const unsigned char* __restrict__ src,
                                                   const int* __restrict__ sidx,
                                                   const int* __restrict__ off,
                                                   float* __restrict__ outf, int nDest) {
    int wave = blockIdx.x * 4 + (threadIdx.x >> 6);
    if (wave >= nDest) return;
    int lane = threadIdx.x & 63;
    int grp = lane >> 3, li = lane & 7;
    int s0 = off[wave], s1 = off[wave + 1];
    unsigned lofs = (unsigned)(li << 4);   // 16 B per lane
    vf2 a0={0,0},a1={0,0},a2={0,0},a3={0,0},a4={0,0},a5={0,0},a6={0,0},a7={0,0};
#define PROC(r) { \
    unsigned o32 = ((unsigned)(r) << 7) + lofs; \
    uint4 q = *(const uint4*)(src + o32); \
    a0 += __builtin_amdgcn_cvt_pk_f32_fp8((int)q.x, false); \
    a1 += __builtin_amdgcn_cvt_pk_f32_fp8((int)q.x, true);  \
    a2 += __builtin_amdgcn_cvt_pk_f32_fp8((int)q.y, false); \
    a3 += __builtin_amdgcn_cvt_pk_f32_fp8((int)q.y, true);  \
    a4 += __builtin_amdgcn_cvt_pk_f32_fp8((int)q.z, false); \
    a5 += __builtin_amdgcn_cvt_pk_f32_fp8((int)q.z, true);  \
    a6 += __builtin_amdgcn_cvt_pk_f32_fp8((int)q.w, false); \
    a7 += __builtin_amdgcn_cvt_pk_f32_fp8((int)q.w, true);  }
    int j = s0;
    for (; j + 32 <= s1; j += 32) {
        int base = j + grp * 4;
        int r0 = sidx[base], r1 = sidx[base + 1], r2 = sidx[base + 2], r3 = sidx[base + 3];
        PROC(r0); PROC(r1); PROC(r2); PROC(r3);
    }
    for (; j + 16 <= s1; j += 16) {
        int base = j + grp * 2;
        int r0 = sidx[base], r1 = sidx[base + 1];
        PROC(r0); PROC(r1);
    }
    {
        int base = j + grp * 2;
        if (base < s1)     PROC(sidx[base]);
        if (base + 1 < s1) PROC(sidx[base + 1]);
    }
#undef PROC
#define RED(v) { v += __shfl_xor(v, 8); v += __shfl_xor(v, 16); v += __shfl_xor(v, 32); }
    RED(a0.x) RED(a0.y) RED(a1.x) RED(a1.y) RED(a2.x) RED(a2.y) RED(a3.x) RED(a3.y)
    RED(a4.x) RED(a4.y) RED(a5.x) RED(a5.y) RED(a6.x) RED(a6.y) RED(a7.x) RED(a7.y)
#undef RED
    int c = s1 - s0;
    float inv = 1.f / (float)(c > 0 ? c : 1);
    if (grp != 0) return;
    float* op = outf + (size_t)wave * 128 + (li << 4);
    ((float4*)op)[0] = make_float4(a0.x * inv, a0.y * inv, a1.x * inv, a1.y * inv);
    ((float4*)op)[1] = make_float4(a2.x * inv, a2.y * inv, a3.x * inv, a3.y * inv);
    ((float4*)op)[2] = make_float4(a4.x * inv, a4.y * inv, a5.x * inv, a5.y * inv);
    ((float4*)op)[3] = make_float4(a6.x * inv, a6.y * inv, a7.x * inv, a7.y * inv);
}

// ============ V-side segment-mean, GROUP-PER-DEST 8-lane, 8-deep pipeline ============
__global__ __launch_bounds__(256) void segred128v8(const unsigned char* __restrict__ src,
                                                   const int* __restrict__ sidx,
                                                   const int* __restrict__ off,
                                                   unsigned char* __restrict__ out8, int nDest) {
    int lane = threadIdx.x & 63;
    int grp = lane >> 3, li = lane & 7;
    int dest = blockIdx.x * 32 + ((threadIdx.x >> 6) << 3) + grp;
    bool valid = dest < nDest;
    int s0 = 0, s1 = 0;
    if (valid) { s0 = off[dest]; s1 = off[dest + 1]; }
    unsigned lofs = (unsigned)(li << 4);   // 16 B per lane
    vf2 a0={0,0},a1={0,0},a2={0,0},a3={0,0},a4={0,0},a5={0,0},a6={0,0},a7={0,0};
#define PROC(r) { \
    unsigned o32 = ((unsigned)(r) << 7) + lofs; \
    uint4 q = *(const uint4*)(src + o32); \
    a0 += __builtin_amdgcn_cvt_pk_f32_fp8((int)q.x, false); \
    a1 += __builtin_amdgcn_cvt_pk_f32_fp8((int)q.x, true);  \
    a2 += __builtin_amdgcn_cvt_pk_f32_fp8((int)q.y, false); \
    a3 += __builtin_amdgcn_cvt_pk_f32_fp8((int)q.y, true);  \
    a4 += __builtin_amdgcn_cvt_pk_f32_fp8((int)q.z, false); \
    a5 += __builtin_amdgcn_cvt_pk_f32_fp8((int)q.z, true);  \
    a6 += __builtin_amdgcn_cvt_pk_f32_fp8((int)q.w, false); \
    a7 += __builtin_amdgcn_cvt_pk_f32_fp8((int)q.w, true);  }
    int j = s0;
    for (; j + 8 <= s1; j += 8) {
        int r0 = sidx[j],     r1 = sidx[j + 1], r2 = sidx[j + 2], r3 = sidx[j + 3];
        int r4 = sidx[j + 4], r5 = sidx[j + 5], r6 = sidx[j + 6], r7 = sidx[j + 7];
        PROC(r0); PROC(r1); PROC(r2); PROC(r3);
        PROC(r4); PROC(r5); PROC(r6); PROC(r7);
    }
    for (; j < s1; ++j) { int r = sidx[j]; PROC(r); }
#undef PROC
    if (!valid) return;
    int c = s1 - s0;
    float inv = 1.f / (float)(c > 0 ? c : 1);
    int w0 = pk8<false>(fmaxf(a0.x * inv, 0.f), fmaxf(a0.y * inv, 0.f), 0);
    w0 = pk8<true>(fmaxf(a1.x * inv, 0.f), fmaxf(a1.y * inv, 0.f), w0);
    int w1 = pk8<false>(fmaxf(a2.x * inv, 0.f), fmaxf(a2.y * inv, 0.f), 0);
    w1 = pk8<true>(fmaxf(a3.x * inv, 0.f), fmaxf(a3.y * inv, 0.f), w1);
    int w2 = pk8<false>(fmaxf(a4.x * inv, 0.f), fmaxf(a4.y * inv, 0.f), 0);
    w2 = pk8<true>(fmaxf(a5.x * inv, 0.f), fmaxf(a5.y * inv, 0.f), w2);
    int w3 = pk8<false>(fmaxf(a6.x * inv, 0.f), fmaxf(a6.y * inv, 0.f), 0);
    w3 = pk8<true>(fmaxf(a7.x * inv, 0.f), fmaxf(a7.y * inv, 0.f), w3);
    *(int4*)(out8 + (size_t)dest * 128 + (li << 4)) = make_int4(w0, w1, w2, w3);
}

// ============ final segment-mean + log_softmax, GROUP-PER-DEST 8-lane, 8-deep ============
__global__ __launch_bounds__(256) void segred40ls(const unsigned short* __restrict__ src,
                                                  const int* __restrict__ sidx,
                                                  const int* __restrict__ off,
                                                  float* __restrict__ out, int nDest) {
    int lane = threadIdx.x & 63;
    int grp = lane >> 3, li = lane & 7;
    int dest = blockIdx.x * 32 + ((threadIdx.x >> 6) << 3) + grp;
    bool valid = dest < nDest;
    int s0 = 0, s1 = 0;
    if (valid) { s0 = off[dest]; s1 = off[dest + 1]; }
    const unsigned short* sp = src + (li << 3);   // 8 ch (16B) per lane; li>=5 reads in-row pad
    float2 a0 = {0.f,0.f}, a1 = {0.f,0.f}, a2 = {0.f,0.f}, a3 = {0.f,0.f};
#define PROC(r) { \
    uint4 q = *(const uint4*)(sp + ((size_t)(unsigned)(r) << 6)); \
    float2 t0 = bfu(q.x), t1 = bfu(q.y), t2 = bfu(q.z), t3 = bfu(q.w); \
    a0.x += t0.x; a0.y += t0.y; a1.x += t1.x; a1.y += t1.y; \
    a2.x += t2.x; a2.y += t2.y; a3.x += t3.x; a3.y += t3.y; }
    int j = s0;
    for (; j + 8 <= s1; j += 8) {
        int r0 = sidx[j],     r1 = sidx[j + 1], r2 = sidx[j + 2], r3 = sidx[j + 3];
        int r4 = sidx[j + 4], r5 = sidx[j + 5], r6 = sidx[j + 6], r7 = sidx[j + 7];
        PROC(r0); PROC(r1); PROC(r2); PROC(r3);
        PROC(r4); PROC(r5); PROC(r6); PROC(r7);
    }
    for (; j < s1; ++j) { int r = sidx[j]; PROC(r); }
#undef PROC
    int c = s1 - s0;
    float inv = 1.f / (float)(c > 0 ? c : 1);
    a0.x *= inv; a0.y *= inv; a1.x *= inv; a1.y *= inv;
    a2.x *= inv; a2.y *= inv; a3.x *= inv; a3.y *= inv;
    bool act = valid && (li < 5);
    float mv = act ? fmaxf(fmaxf(fmaxf(a0.x, a0.y), fmaxf(a1.x, a1.y)),
                           fmaxf(fmaxf(a2.x, a2.y), fmaxf(a3.x, a3.y))) : -INFINITY;
#pragma unroll
    for (int o = 1; o < 8; o <<= 1) mv = fmaxf(mv, __shfl_xor(mv, o, 8));
    float e = act ? (__expf(a0.x - mv) + __expf(a0.y - mv) + __expf(a1.x - mv) + __expf(a1.y - mv) +
                     __expf(a2.x - mv) + __expf(a2.y - mv) + __expf(a3.x - mv) + __expf(a3.y - mv)) : 0.f;
#pragma unroll
    for (int o = 1; o < 8; o <<= 1) e += __shfl_xor(e, o, 8);
    float ls = __logf(e);
    if (act) {
        float* op = out + (size_t)dest * 40 + (li << 3);
        *(float4*)op = make_float4(a0.x - mv - ls, a0.y - mv - ls, a1.x - mv - ls, a1.y - mv - ls);
        *(float4*)(op + 4) = make_float4(a2.x - mv - ls, a2.y - mv - ls, a3.x - mv - ls, a3.y - mv - ls);
    }
}

extern "C" void kernel_launch(void* const* d_in, const int* in_sizes, int n_in,
                              void* d_out, int out_size, void* d_ws, size_t ws_size,
                              hipStream_t stream) {
    const float* x    = (const float*)d_in[0];
    const int*   vids = (const int*)d_in[1];
    const int*   eids = (const int*)d_in[2];
    const float* w1a  = (const float*)d_in[3];
    const float* w1b  = (const float*)d_in[4];
    const float* w2a  = (const float*)d_in[5];
    const float* w2b  = (const float*)d_in[6];
    const float* g    = (const float*)d_in[7];
    const float* bta  = (const float*)d_in[8];
    const float* mu   = (const float*)d_in[9];
    const float* var  = (const float*)d_in[10];
    float* out = (float*)d_out;
    char*  ws  = (char*)d_ws;

    // ---- workspace layout (peak ~106.2 MB) ----
    int*            srcE = (int*)(ws);                        //  0      .. 12.8M
    int*            srcV = (int*)(ws + 12800000);             // 12.8M   .. 25.6M
    unsigned char*  xh8  = (unsigned char*)(ws + 25600000);   // V*128 fp8 = 12.8 MB -> 38.4M
    unsigned char*  hh8  = (unsigned char*)(ws + 38400000);   // V*128 fp8 = 12.8 MB -> 51.2M
    unsigned*       pkE  = (unsigned*)(ws + 51200000);        // 14.47 MB (dead after s4)
    unsigned*       pkV  = (unsigned*)(ws + 65670000);        // 14.05 MB (dead after s4)
    float*          mE   = (float*)(ws + 76800000);           // E*128 f32 (after s4)
    unsigned char*  y28  = (unsigned char*)(ws + 97280000);   // E*128 fp8 = 2.56 MB (L2-resident)
    unsigned short* y4h  = (unsigned short*)(ws + 103040000); // E*64 bf16 = 2.56 MB (stride-64)
    int*            offE = (int*)(ws + 105600000);            // NE+1
    int*            offV = (int*)(ws + 105680128);            // NV+1
    int*            bbE  = (int*)(ws + 106080256);            // 257
    int*            bbV  = (int*)(ws + 106081536);            // 257
    int*            gcE  = (int*)(ws + 106082816);            // 256
    int*            gcV  = (int*)(ws + 106083840);            // 256 (contiguous with gcE)
    float*          w2af = (float*)(ws + 106087424);          // 128*40 f32
    float*          bias = (float*)(ws + 106107904);          // 40 f32

    // ---- CSR build + x->fp8 (merged into one grid) ----
    (void)hipMemsetAsync(gcE, 0, 512 * 4, stream);            // gcE+gcV
    s3_bin_cvt<<<NBLK2 + CVTB, 1024, 0, stream>>>(vids, eids, gcE, gcV, pkE, pkV, x, xh8);
    s2_scan<<<1, 128, 0, stream>>>(gcE, gcV, bbE, bbV, offE, offV,
                                   g, bta, mu, var, w2a, w2af, bias);
    s4_sort<<<NBE + NBV, 1024, 0, stream>>>(pkE, pkV, bbE, bbV, offE, offV, srcE, srcV);

    // ---- layer 1 (mean first; fused matmul pair on E rows) ----
    segred128e8<<<(NE + 3) / 4, 256, 0, stream>>>(xh8, srcE, offE, mE, NE);
    mm12<<<(NE + 31) / 32, 256, 0, stream>>>(mE, w1a, w1b, y28, NE);
    segred128v8<<<(NV + 31) / 32, 256, 0, stream>>>(y28, srcV, offV, hh8, NV);  // relu(mean) only

    // ---- layer 2 (second linearity swap; BN folded into w2af/bias; fused n40 matmuls) ----
    segred128e8<<<(NE + 3) / 4, 256, 0, stream>>>(hh8, srcE, offE, mE, NE);
    mm_fused40<<<(NE + 23) / 24, 256, 0, stream>>>(mE, w2af, bias, w2b, y4h, NE);
    segred40ls<<<(NV + 31) / 32, 256, 0, stream>>>(y4h, srcV, offV, out, NV);
}

// Round 20
// 318.702 us; speedup vs baseline: 1.0355x; 1.0355x over previous
//
#include <hip/hip_runtime.h>
#include <hip/hip_bf16.h>

#define NV 100000
#define NE 20000
#define NNZ 3200000
#define CHUNK2 8192
#define NBLK2 ((NNZ + CHUNK2 - 1) / CHUNK2)  // 391 (s3 part)
#define CVTB ((NV * 16 + 511) / 512)         // 3125 (cvt part)
#define NBE 157      // E buckets: e>>7
#define NBV 196      // V buckets: v>>9
#define CAPE 23040
#define CAPV 17920

typedef float vf2 __attribute__((ext_vector_type(2)));

__device__ __forceinline__ unsigned short f2bf(float f) {
    unsigned u = __float_as_uint(f);
    u += 0x7fffu + ((u >> 16) & 1u);       // round-to-nearest-even
    return (unsigned short)(u >> 16);
}
__device__ __forceinline__ float2 bfu(unsigned u) {
    return make_float2(__uint_as_float(u << 16), __uint_as_float(u & 0xffff0000u));
}
template <bool HI>
__device__ __forceinline__ int pk8(float a, float b, int old) {
    return __builtin_amdgcn_cvt_pk_fp8_f32(a, b, old, HI);
}

// ---------------- S3 + cvt merged: blocks [0,NBLK2) bin; blocks [NBLK2, NBLK2+CVTB) convert x ----
__global__ __launch_bounds__(512) void s3_bin_cvt(const int* __restrict__ vids,
                                                  const int* __restrict__ eids,
                                                  int* __restrict__ gcurE, int* __restrict__ gcurV,
                                                  unsigned* __restrict__ pkE, unsigned* __restrict__ pkV,
                                                  const float* __restrict__ xin,
                                                  unsigned char* __restrict__ xh8) {
    __shared__ int h[256], sc[256], gp[256];
    __shared__ unsigned staged[CHUNK2];        // 32 KB
    __shared__ unsigned char sb[CHUNK2];       // 8 KB
    int tid = threadIdx.x;
    if (blockIdx.x >= NBLK2) {
        // ---- cvt part ----
        int i = (blockIdx.x - NBLK2) * 512 + tid;
        if (i < NV * 16) {
            float4 v0 = ((const float4*)xin)[i * 2];
            float4 v1 = ((const float4*)xin)[i * 2 + 1];
            int lo = pk8<false>(v0.x, v0.y, 0); lo = pk8<true>(v0.z, v0.w, lo);
            int hi = pk8<false>(v1.x, v1.y, 0); hi = pk8<true>(v1.z, v1.w, hi);
            ((int2*)xh8)[i] = make_int2(lo, hi);
        }
        return;
    }
    int base = blockIdx.x * CHUNK2;
    int n = NNZ - base; if (n > CHUNK2) n = CHUNK2;
    unsigned pe[16], pv[16];
#pragma unroll
    for (int k = 0; k < 16; ++k) {
        int i = base + k * 512 + tid;
        pe[k] = 0u; pv[k] = 0u;
        if (i < NNZ) {
            unsigned e = (unsigned)eids[i], v = (unsigned)vids[i];
            pe[k] = (e << 17) | v;
            pv[k] = (v << 15) | e;
        }
    }
#define SIDE(pk_arr, PK, gcur, CAP) \
    { \
        if (tid < 256) h[tid] = 0; \
        __syncthreads(); \
        _Pragma("unroll") \
        for (int k = 0; k < 16; ++k) \
            if (base + k * 512 + tid < NNZ) atomicAdd(&h[PK[k] >> 24], 1); \
        __syncthreads(); \
        if (tid < 256) sc[tid] = h[tid]; \
        __syncthreads(); \
        for (int o = 1; o < 256; o <<= 1) { \
            int v = (tid >= o && tid < 256) ? sc[tid - o] : 0; \
            __syncthreads(); \
            if (tid < 256) sc[tid] += v; \
            __syncthreads(); \
        } \
        if (tid < 256) { int ex = sc[tid] - h[tid]; h[tid] = ex; sc[tid] = ex; } \
        __syncthreads(); \
        _Pragma("unroll") \
        for (int k = 0; k < 16; ++k) \
            if (base + k * 512 + tid < NNZ) { \
                int b = PK[k] >> 24; \
                int pos = atomicAdd(&h[b], 1); \
                staged[pos] = PK[k]; sb[pos] = (unsigned char)b; \
            } \
        __syncthreads(); \
        if (tid < 256) { int cnt = h[tid] - sc[tid]; gp[tid] = cnt ? atomicAdd(&gcur[tid], cnt) : 0; } \
        __syncthreads(); \
        for (int i = tid; i < n; i += 512) { \
            int b = sb[i]; \
            pk_arr[(size_t)b * CAP + gp[b] + (i - sc[b])] = staged[i]; \
        } \
        __syncthreads(); \
    }
    SIDE(pkE, pe, gcurE, CAPE)
    SIDE(pkV, pv, gcurV, CAPV)
#undef SIDE
}

// ---------------- S2: scan bucket FILL COUNTS -> output bases; BN fold + w2a fold ----------------
__global__ void s2_scan(const int* __restrict__ gcurE, const int* __restrict__ gcurV,
                        int* __restrict__ bbE, int* __restrict__ bbV,
                        int* __restrict__ offE, int* __restrict__ offV,
                        const float* __restrict__ g, const float* __restrict__ b,
                        const float* __restrict__ mu, const float* __restrict__ var,
                        const float* __restrict__ w2a,
                        float* __restrict__ w2af, float* __restrict__ bias) {
    __shared__ float sh_s[128];
    int t = threadIdx.x;
    if (t < 128) {
        float sc = g[t] * rsqrtf(var[t] + 1e-5f);
        float sh = b[t] - mu[t] * sc;
        sh_s[t] = sh;
        for (int n = 0; n < 40; ++n)
            w2af[t * 40 + n] = sc * w2a[t * 40 + n];
    }
    __syncthreads();
    if (t < 40) {
        float acc = 0.f;
        for (int c = 0; c < 128; ++c)
            acc = fmaf(sh_s[c], w2a[c * 40 + t], acc);
        bias[t] = acc;
    }
    if (t == 0) {
        int run = 0;
        for (int bb = 0; bb < 256; ++bb) { bbE[bb] = run; run += gcurE[bb]; }
        bbE[256] = run; offE[NE] = run;
    } else if (t == 1) {
        int run = 0;
        for (int bb = 0; bb < 256; ++bb) { bbV[bb] = run; run += gcurV[bb]; }
        bbV[256] = run; offV[NV] = run;
    }
}

// ---------------- S4: per-bucket fine counting sort (reads fixed-cap bucket, writes CSR) ----
__global__ __launch_bounds__(1024) void s4_sort(const unsigned* __restrict__ pkE,
                                                const unsigned* __restrict__ pkV,
                                                const int* __restrict__ bbE, const int* __restrict__ bbV,
                                                int* __restrict__ offE, int* __restrict__ offV,
                                                int* __restrict__ srcE, int* __restrict__ srcV) {
    __shared__ int h[512], sc[512];
    int blk = blockIdx.x, tid = threadIdx.x;
    bool isE = blk < NBE;
    const unsigned* pk = isE ? pkE : pkV;
    const int* bb = isE ? bbE : bbV;
    int* off = isE ? offE : offV;
    int* srcO = isE ? srcE : srcV;
    int b = isE ? blk : blk - NBE;
    int NLOC = isE ? 128 : 512;
    int SH = isE ? 17 : 15;
    int LM = NLOC - 1;
    unsigned PM = isE ? 0x1FFFFu : 0x7FFFu;
    int d0 = isE ? (b << 7) : (b << 9);
    int nD = isE ? NE : NV;
    size_t inBase = (size_t)b * (isE ? CAPE : CAPV);
    int obase = bb[b];
    int cnt = bb[b + 1] - obase;
    if (tid < NLOC) h[tid] = 0;
    __syncthreads();
    for (int i = tid; i < cnt; i += 1024)
        atomicAdd(&h[(pk[inBase + i] >> SH) & LM], 1);
    __syncthreads();
    if (tid < NLOC) sc[tid] = h[tid];
    __syncthreads();
    for (int o = 1; o < NLOC; o <<= 1) {
        int v = (tid >= o && tid < NLOC) ? sc[tid - o] : 0;
        __syncthreads();
        if (tid < NLOC) sc[tid] += v;
        __syncthreads();
    }
    if (tid < NLOC) {
        int ex = sc[tid] - h[tid];
        int d = d0 + tid;
        if (d < nD) off[d] = obase + ex;
        h[tid] = ex;
    }
    __syncthreads();
    for (int i = tid; i < cnt; i += 1024) {
        unsigned p = pk[inBase + i];
        int pos = atomicAdd(&h[(p >> SH) & LM], 1);
        srcO[obase + pos] = (int)(p & PM);
    }
}

// ---------------- FUSED: y = relu(A@W1); y28 = fp8(y@W2); sequential LDS reuse (80 KB) ----------
__global__ __launch_bounds__(256) void mm12(const float* __restrict__ A,
                                            const float* __restrict__ W1,
                                            const float* __restrict__ W2,
                                            unsigned char* __restrict__ out8, int M) {
    __shared__ float Wl[128 * 128];   // 64 KB (W1, then W2)
    __shared__ float Al[32 * 128];    // 16 KB (A tile, then Y tile)
    int tid = threadIdx.x;
    for (int i = tid; i < 4096; i += 256)
        ((float4*)Wl)[i] = ((const float4*)W1)[i];
    int row0 = blockIdx.x * 32;
    for (int i = tid; i < 1024; i += 256) {
        int r = i >> 5, c4 = i & 31;
        int row = row0 + r;
        float4 v = make_float4(0.f, 0.f, 0.f, 0.f);
        if (row < M) v = ((const float4*)(A + (size_t)row * 128))[c4];
        ((float4*)Al)[i] = v;
    }
    __syncthreads();
    int cx = (tid & 31) * 4;
    int rg = (tid >> 5) * 4;
    float acc[4][4] = {};
#pragma unroll 8
    for (int k = 0; k < 128; ++k) {
        float4 w = *(const float4*)&Wl[k * 128 + cx];
#pragma unroll
        for (int r = 0; r < 4; ++r) {
            float a = Al[(rg + r) * 128 + k];
            acc[r][0] = fmaf(a, w.x, acc[r][0]);
            acc[r][1] = fmaf(a, w.y, acc[r][1]);
            acc[r][2] = fmaf(a, w.z, acc[r][2]);
            acc[r][3] = fmaf(a, w.w, acc[r][3]);
        }
    }
    __syncthreads();   // all reads of Al/Wl done
#pragma unroll
    for (int r = 0; r < 4; ++r)
        *(float4*)&Al[(rg + r) * 128 + cx] =
            make_float4(fmaxf(acc[r][0], 0.f), fmaxf(acc[r][1], 0.f),
                        fmaxf(acc[r][2], 0.f), fmaxf(acc[r][3], 0.f));
    for (int i = tid; i < 4096; i += 256)
        ((float4*)Wl)[i] = ((const float4*)W2)[i];
    __syncthreads();
    float acc2[4][4] = {};
#pragma unroll 8
    for (int k = 0; k < 128; ++k) {
        float4 w = *(const float4*)&Wl[k * 128 + cx];
#pragma unroll
        for (int r = 0; r < 4; ++r) {
            float a = Al[(rg + r) * 128 + k];
            acc2[r][0] = fmaf(a, w.x, acc2[r][0]);
            acc2[r][1] = fmaf(a, w.y, acc2[r][1]);
            acc2[r][2] = fmaf(a, w.z, acc2[r][2]);
            acc2[r][3] = fmaf(a, w.w, acc2[r][3]);
        }
    }
#pragma unroll
    for (int r = 0; r < 4; ++r) {
        int row = row0 + rg + r;
        if (row < M) {
            int pw = pk8<false>(acc2[r][0], acc2[r][1], 0);
            pw = pk8<true>(acc2[r][2], acc2[r][3], pw);
            *(int*)&out8[(size_t)row * 128 + cx] = pw;
        }
    }
}

// ---------------- FUSED: y3 = relu(A@W' + bias) in LDS; y4 = y3@W2 -> bf16 (stride-64) ----------
__global__ __launch_bounds__(256) void mm_fused40(const float* __restrict__ A,
                                                  const float* __restrict__ W1,
                                                  const float* __restrict__ bias,
                                                  const float* __restrict__ W2,
                                                  unsigned short* __restrict__ out16, int M) {
    __shared__ float Wl[128 * 40];    // 20 KB
    __shared__ float W2l[1600];       // 6.4 KB
    __shared__ float Al[24 * 128];    // 12 KB
    __shared__ float Yl[24 * 40];     // 3.84 KB
    int tid = threadIdx.x;
    for (int i = tid; i < 1280; i += 256)
        ((float4*)Wl)[i] = ((const float4*)W1)[i];
    for (int i = tid; i < 400; i += 256)
        ((float4*)W2l)[i] = ((const float4*)W2)[i];
    int row0 = blockIdx.x * 24;
    for (int i = tid; i < 768; i += 256) {
        int r = i >> 5, c4 = i & 31;
        int row = row0 + r;
        float4 v = make_float4(0.f, 0.f, 0.f, 0.f);
        if (row < M) v = ((const float4*)(A + (size_t)row * 128))[c4];
        ((float4*)Al)[i] = v;
    }
    __syncthreads();
    if (tid < 240) {
        int col = tid % 40;
        int rg = (tid / 40) * 4;
        float b0 = bias[col];
        float acc[4] = {b0, b0, b0, b0};
#pragma unroll 8
        for (int k = 0; k < 128; ++k) {
            float w = Wl[k * 40 + col];
#pragma unroll
            for (int r = 0; r < 4; ++r)
                acc[r] = fmaf(Al[(rg + r) * 128 + k], w, acc[r]);
        }
#pragma unroll
        for (int r = 0; r < 4; ++r)
            Yl[(rg + r) * 40 + col] = fmaxf(acc[r], 0.f);
    }
    __syncthreads();
    for (int idx = tid; idx < 960; idx += 256) {
        int row = idx / 40, col = idx % 40;
        float acc = 0.f;
#pragma unroll
        for (int k = 0; k < 40; ++k)
            acc = fmaf(Yl[row * 40 + k], W2l[k * 40 + col], acc);
        int grow = row0 + row;
        if (grow < M) out16[(size_t)grow * 64 + col] = f2bf(acc);
    }
}

// ============ E-side segment-mean, 128 fp8 ch, 8-lane groups, 4-deep MLP ============
__global__ __launch_bounds__(256) void segred128e8(const unsigned char* __restrict__ src,
                                                   const int* __restrict__ sidx,
                                                   const int* __restrict__ off,
                                                   float* __restrict__ outf, int nDest) {
    int wave = blockIdx.x * 4 + (threadIdx.x >> 6);
    if (wave >= nDest) return;
    int lane = threadIdx.x & 63;
    int grp = lane >> 3, li = lane & 7;
    int s0 = off[wave], s1 = off[wave + 1];
    unsigned lofs = (unsigned)(li << 4);   // 16 B per lane
    vf2 a0={0,0},a1={0,0},a2={0,0},a3={0,0},a4={0,0},a5={0,0},a6={0,0},a7={0,0};
#define PROC(r) { \
    unsigned o32 = ((unsigned)(r) << 7) + lofs; \
    uint4 q = *(const uint4*)(src + o32); \
    a0 += __builtin_amdgcn_cvt_pk_f32_fp8((int)q.x, false); \
    a1 += __builtin_amdgcn_cvt_pk_f32_fp8((int)q.x, true);  \
    a2 += __builtin_amdgcn_cvt_pk_f32_fp8((int)q.y, false); \
    a3 += __builtin_amdgcn_cvt_pk_f32_fp8((int)q.y, true);  \
    a4 += __builtin_amdgcn_cvt_pk_f32_fp8((int)q.z, false); \
    a5 += __builtin_amdgcn_cvt_pk_f32_fp8((int)q.z, true);  \
    a6 += __builtin_amdgcn_cvt_pk_f32_fp8((int)q.w, false); \
    a7 += __builtin_amdgcn_cvt_pk_f32_fp8((int)q.w, true);  }
    int j = s0;
    for (; j + 32 <= s1; j += 32) {
        int base = j + grp * 4;
        int r0 = sidx[base], r1 = sidx[base + 1], r2 = sidx[base + 2], r3 = sidx[base + 3];
        PROC(r0); PROC(r1); PROC(r2); PROC(r3);
    }
    for (; j + 16 <= s1; j += 16) {
        int base = j + grp * 2;
        int r0 = sidx[base], r1 = sidx[base + 1];
        PROC(r0); PROC(r1);
    }
    {
        int base = j + grp * 2;
        if (base < s1)     PROC(sidx[base]);
        if (base + 1 < s1) PROC(sidx[base + 1]);
    }
#undef PROC
#define RED(v) { v += __shfl_xor(v, 8); v += __shfl_xor(v, 16); v += __shfl_xor(v, 32); }
    RED(a0.x) RED(a0.y) RED(a1.x) RED(a1.y) RED(a2.x) RED(a2.y) RED(a3.x) RED(a3.y)
    RED(a4.x) RED(a4.y) RED(a5.x) RED(a5.y) RED(a6.x) RED(a6.y) RED(a7.x) RED(a7.y)
#undef RED
    int c = s1 - s0;
    float inv = 1.f / (float)(c > 0 ? c : 1);
    if (grp != 0) return;
    float* op = outf + (size_t)wave * 128 + (li << 4);
    ((float4*)op)[0] = make_float4(a0.x * inv, a0.y * inv, a1.x * inv, a1.y * inv);
    ((float4*)op)[1] = make_float4(a2.x * inv, a2.y * inv, a3.x * inv, a3.y * inv);
    ((float4*)op)[2] = make_float4(a4.x * inv, a4.y * inv, a5.x * inv, a5.y * inv);
    ((float4*)op)[3] = make_float4(a6.x * inv, a6.y * inv, a7.x * inv, a7.y * inv);
}

// ============ V-side segment-mean, GROUP-PER-DEST 8-lane (uint4 = 16 ch/lane), no reduce ============
__global__ __launch_bounds__(256) void segred128v8(const unsigned char* __restrict__ src,
                                                   const int* __restrict__ sidx,
                                                   const int* __restrict__ off,
                                                   unsigned char* __restrict__ out8, int nDest) {
    int lane = threadIdx.x & 63;
    int grp = lane >> 3, li = lane & 7;
    int dest = blockIdx.x * 32 + ((threadIdx.x >> 6) << 3) + grp;
    bool valid = dest < nDest;
    int s0 = 0, s1 = 0;
    if (valid) { s0 = off[dest]; s1 = off[dest + 1]; }
    unsigned lofs = (unsigned)(li << 4);   // 16 B per lane
    vf2 a0={0,0},a1={0,0},a2={0,0},a3={0,0},a4={0,0},a5={0,0},a6={0,0},a7={0,0};
#define PROC(r) { \
    unsigned o32 = ((unsigned)(r) << 7) + lofs; \
    uint4 q = *(const uint4*)(src + o32); \
    a0 += __builtin_amdgcn_cvt_pk_f32_fp8((int)q.x, false); \
    a1 += __builtin_amdgcn_cvt_pk_f32_fp8((int)q.x, true);  \
    a2 += __builtin_amdgcn_cvt_pk_f32_fp8((int)q.y, false); \
    a3 += __builtin_amdgcn_cvt_pk_f32_fp8((int)q.y, true);  \
    a4 += __builtin_amdgcn_cvt_pk_f32_fp8((int)q.z, false); \
    a5 += __builtin_amdgcn_cvt_pk_f32_fp8((int)q.z, true);  \
    a6 += __builtin_amdgcn_cvt_pk_f32_fp8((int)q.w, false); \
    a7 += __builtin_amdgcn_cvt_pk_f32_fp8((int)q.w, true);  }
    int j = s0;
    for (; j + 4 <= s1; j += 4) {
        int r0 = sidx[j], r1 = sidx[j + 1], r2 = sidx[j + 2], r3 = sidx[j + 3];
        PROC(r0); PROC(r1); PROC(r2); PROC(r3);
    }
    for (; j < s1; ++j) { int r = sidx[j]; PROC(r); }
#undef PROC
    if (!valid) return;
    int c = s1 - s0;
    float inv = 1.f / (float)(c > 0 ? c : 1);
    int w0 = pk8<false>(fmaxf(a0.x * inv, 0.f), fmaxf(a0.y * inv, 0.f), 0);
    w0 = pk8<true>(fmaxf(a1.x * inv, 0.f), fmaxf(a1.y * inv, 0.f), w0);
    int w1 = pk8<false>(fmaxf(a2.x * inv, 0.f), fmaxf(a2.y * inv, 0.f), 0);
    w1 = pk8<true>(fmaxf(a3.x * inv, 0.f), fmaxf(a3.y * inv, 0.f), w1);
    int w2 = pk8<false>(fmaxf(a4.x * inv, 0.f), fmaxf(a4.y * inv, 0.f), 0);
    w2 = pk8<true>(fmaxf(a5.x * inv, 0.f), fmaxf(a5.y * inv, 0.f), w2);
    int w3 = pk8<false>(fmaxf(a6.x * inv, 0.f), fmaxf(a6.y * inv, 0.f), 0);
    w3 = pk8<true>(fmaxf(a7.x * inv, 0.f), fmaxf(a7.y * inv, 0.f), w3);
    *(int4*)(out8 + (size_t)dest * 128 + (li << 4)) = make_int4(w0, w1, w2, w3);
}

// ============ final segment-mean + log_softmax, GROUP-PER-DEST 8-lane (uint4 = 8 ch/lane) ============
__global__ __launch_bounds__(256) void segred40ls(const unsigned short* __restrict__ src,
                                                  const int* __restrict__ sidx,
                                                  const int* __restrict__ off,
                                                  float* __restrict__ out, int nDest) {
    int lane = threadIdx.x & 63;
    int grp = lane >> 3, li = lane & 7;
    int dest = blockIdx.x * 32 + ((threadIdx.x >> 6) << 3) + grp;
    bool valid = dest < nDest;
    int s0 = 0, s1 = 0;
    if (valid) { s0 = off[dest]; s1 = off[dest + 1]; }
    const unsigned short* sp = src + (li << 3);   // 8 ch (16B) per lane; li>=5 reads in-row pad
    float2 a0 = {0.f,0.f}, a1 = {0.f,0.f}, a2 = {0.f,0.f}, a3 = {0.f,0.f};
#define PROC(r) { \
    uint4 q = *(const uint4*)(sp + ((size_t)(unsigned)(r) << 6)); \
    float2 t0 = bfu(q.x), t1 = bfu(q.y), t2 = bfu(q.z), t3 = bfu(q.w); \
    a0.x += t0.x; a0.y += t0.y; a1.x += t1.x; a1.y += t1.y; \
    a2.x += t2.x; a2.y += t2.y; a3.x += t3.x; a3.y += t3.y; }
    int j = s0;
    for (; j + 4 <= s1; j += 4) {
        int r0 = sidx[j], r1 = sidx[j + 1], r2 = sidx[j + 2], r3 = sidx[j + 3];
        PROC(r0); PROC(r1); PROC(r2); PROC(r3);
    }
    for (; j < s1; ++j) { int r = sidx[j]; PROC(r); }
#undef PROC
    int c = s1 - s0;
    float inv = 1.f / (float)(c > 0 ? c : 1);
    a0.x *= inv; a0.y *= inv; a1.x *= inv; a1.y *= inv;
    a2.x *= inv; a2.y *= inv; a3.x *= inv; a3.y *= inv;
    bool act = valid && (li < 5);
    float mv = act ? fmaxf(fmaxf(fmaxf(a0.x, a0.y), fmaxf(a1.x, a1.y)),
                           fmaxf(fmaxf(a2.x, a2.y), fmaxf(a3.x, a3.y))) : -INFINITY;
#pragma unroll
    for (int o = 1; o < 8; o <<= 1) mv = fmaxf(mv, __shfl_xor(mv, o, 8));
    float e = act ? (__expf(a0.x - mv) + __expf(a0.y - mv) + __expf(a1.x - mv) + __expf(a1.y - mv) +
                     __expf(a2.x - mv) + __expf(a2.y - mv) + __expf(a3.x - mv) + __expf(a3.y - mv)) : 0.f;
#pragma unroll
    for (int o = 1; o < 8; o <<= 1) e += __shfl_xor(e, o, 8);
    float ls = __logf(e);
    if (act) {
        float* op = out + (size_t)dest * 40 + (li << 3);
        *(float4*)op = make_float4(a0.x - mv - ls, a0.y - mv - ls, a1.x - mv - ls, a1.y - mv - ls);
        *(float4*)(op + 4) = make_float4(a2.x - mv - ls, a2.y - mv - ls, a3.x - mv - ls, a3.y - mv - ls);
    }
}

extern "C" void kernel_launch(void* const* d_in, const int* in_sizes, int n_in,
                              void* d_out, int out_size, void* d_ws, size_t ws_size,
                              hipStream_t stream) {
    const float* x    = (const float*)d_in[0];
    const int*   vids = (const int*)d_in[1];
    const int*   eids = (const int*)d_in[2];
    const float* w1a  = (const float*)d_in[3];
    const float* w1b  = (const float*)d_in[4];
    const float* w2a  = (const float*)d_in[5];
    const float* w2b  = (const float*)d_in[6];
    const float* g    = (const float*)d_in[7];
    const float* bta  = (const float*)d_in[8];
    const float* mu   = (const float*)d_in[9];
    const float* var  = (const float*)d_in[10];
    float* out = (float*)d_out;
    char*  ws  = (char*)d_ws;

    // ---- workspace layout (peak ~106.2 MB) ----
    int*            srcE = (int*)(ws);                        //  0      .. 12.8M
    int*            srcV = (int*)(ws + 12800000);             // 12.8M   .. 25.6M
    unsigned char*  xh8  = (unsigned char*)(ws + 25600000);   // V*128 fp8 = 12.8 MB -> 38.4M
    unsigned char*  hh8  = (unsigned char*)(ws + 38400000);   // V*128 fp8 = 12.8 MB -> 51.2M
    unsigned*       pkE  = (unsigned*)(ws + 51200000);        // 14.47 MB (dead after s4)
    unsigned*       pkV  = (unsigned*)(ws + 65670000);        // 14.05 MB (dead after s4)
    float*          mE   = (float*)(ws + 76800000);           // E*128 f32 (after s4)
    unsigned char*  y28  = (unsigned char*)(ws + 97280000);   // E*128 fp8 = 2.56 MB (L2-resident)
    unsigned short* y4h  = (unsigned short*)(ws + 103040000); // E*64 bf16 = 2.56 MB (stride-64)
    int*            offE = (int*)(ws + 105600000);            // NE+1
    int*            offV = (int*)(ws + 105680128);            // NV+1
    int*            bbE  = (int*)(ws + 106080256);            // 257
    int*            bbV  = (int*)(ws + 106081536);            // 257
    int*            gcE  = (int*)(ws + 106082816);            // 256
    int*            gcV  = (int*)(ws + 106083840);            // 256 (contiguous with gcE)
    float*          w2af = (float*)(ws + 106087424);          // 128*40 f32
    float*          bias = (float*)(ws + 106107904);          // 40 f32

    // ---- CSR build + x->fp8 (merged into one grid) ----
    (void)hipMemsetAsync(gcE, 0, 512 * 4, stream);            // gcE+gcV
    s3_bin_cvt<<<NBLK2 + CVTB, 512, 0, stream>>>(vids, eids, gcE, gcV, pkE, pkV, x, xh8);
    s2_scan<<<1, 128, 0, stream>>>(gcE, gcV, bbE, bbV, offE, offV,
                                   g, bta, mu, var, w2a, w2af, bias);
    s4_sort<<<NBE + NBV, 1024, 0, stream>>>(pkE, pkV, bbE, bbV, offE, offV, srcE, srcV);

    // ---- layer 1 (mean first; fused matmul pair on E rows) ----
    segred128e8<<<(NE + 3) / 4, 256, 0, stream>>>(xh8, srcE, offE, mE, NE);
    mm12<<<(NE + 31) / 32, 256, 0, stream>>>(mE, w1a, w1b, y28, NE);
    segred128v8<<<(NV + 31) / 32, 256, 0, stream>>>(y28, srcV, offV, hh8, NV);  // relu(mean) only

    // ---- layer 2 (second linearity swap; BN folded into w2af/bias; fused n40 matmuls) ----
    segred128e8<<<(NE + 3) / 4, 256, 0, stream>>>(hh8, srcE, offE, mE, NE);
    mm_fused40<<<(NE + 23) / 24, 256, 0, stream>>>(mE, w2af, bias, w2b, y4h, NE);
    segred40ls<<<(NV + 31) / 32, 256, 0, stream>>>(y4h, srcV, offV, out, NV);
}